// Round 4
// baseline (84.149 us; speedup 1.0000x reference)
//
#include <hip/hip_runtime.h>

// WaveletMixing: out = x + IDWT3(scale(DWT3(x))) along N per (b,d) channel.
// x: (B=8, N=4096, D=768) f32.
// Block = 8 channels x 128 output samples (+halo). Full pipeline in LDS.
// Global phases: lane = channel-fast (coalesced float4).
// Compute phases: lane = (c2 = tid>>5, i2 = tid&31) + odd LDS strides ->
//   every LDS access pattern is exactly 2 lanes/bank (free on CDNA4).
// T=128 -> 18.1 KB LDS -> 8 blocks/CU = 100% occupancy (latency hiding).

namespace {

constexpr int NT  = 256;
constexpr int N0  = 4096;
constexpr int DCH = 768;
constexpr int G   = 8;              // channels per block
constexpr int T   = 128;            // output samples per block
constexpr int NTI = N0 / T;         // 32
constexpr int NDG = DCH / G;        // 96

constexpr int L1v = 2051, L2v = 1029, L3v = 518;  // pywt symmetric lengths

// Extended (tile-relative) ranges; stride per channel is ODD (bank freedom).
constexpr int XLO = -42; constexpr int CX = T + 90;    // 218: [n0-42, n0+T+47]
constexpr int SX  = CX + 1;         // 219
constexpr int A1LO = -18; constexpr int C1 = T / 2 + 42;  // 106
constexpr int S1   = 2 * C1 + 1;    // 213: [a (C1) | d (C1)] per channel
constexpr int A2LO = -6;  constexpr int C2 = T / 4 + 18;  // 50
constexpr int S2   = 2 * C2 + 1;    // 101
constexpr int C3   = T / 8 + 6;     // 22 (A3LO = 0)
constexpr int S3   = 2 * C3 + 1;    // 45
// LDS floats: 8*(219+213+101+45) = 4624 -> 18.1 KB -> 8 blocks/CU.

// db4 analysis filters ascending (pywt); HI[k] = (-1)^(k+1)*LO[7-k].
__device__ constexpr float LO[8] = {
  -0.010597401784997278f,  0.032883011666982945f,  0.030841381835986965f,
  -0.18703481171888114f,  -0.02798376941698385f,   0.6308807679295904f,
   0.7148465705525415f,    0.23037781330885523f };
__device__ constexpr float HI[8] = {
  -0.23037781330885523f,   0.7148465705525415f,   -0.6308807679295904f,
  -0.02798376941698385f,   0.18703481171888114f,   0.030841381835986965f,
  -0.032883011666982945f, -0.010597401784997278f };
// Flipped (ascending-address) copies: F[7-k].
__device__ constexpr float LOF[8] = {
   0.23037781330885523f,   0.7148465705525415f,    0.6308807679295904f,
  -0.02798376941698385f,  -0.18703481171888114f,   0.030841381835986965f,
   0.032883011666982945f, -0.010597401784997278f };
__device__ constexpr float HIF[8] = {
  -0.010597401784997278f, -0.032883011666982945f,  0.030841381835986965f,
   0.18703481171888114f,  -0.02798376941698385f,  -0.6308807679295904f,
   0.7148465705525415f,   -0.23037781330885523f };

__device__ __forceinline__ int refl(int g, int n) {
  g = (g < 0) ? (-g - 1) : g;
  return (g >= n) ? (2 * n - 1 - g) : g;
}

// One analysis level. Output coeff p (storage) = abs index loout_abs+p,
// reflected into [0,lenout). Reads 8 consecutive floats (mergeable);
// writes a/d at dword distance cout (<255, mergeable to ds_write2_b32).
__device__ __forceinline__ void analyze(const float* __restrict__ in, int sin_,
                                        int loin_abs, float* __restrict__ outs,
                                        int sout, int cout, int loout_abs,
                                        int lenout, int c, int i) {
  for (int p = i; p < cout; p += 32) {
    const int gp = refl(loout_abs + p, lenout);
    const int qb = 2 * gp + 1 - loin_abs;       // top tap (storage coords)
    const float* __restrict__ s = in + c * sin_ + qb - 7;
    float alo = 0.f, ahi = 0.f;
#pragma unroll
    for (int k = 0; k < 8; ++k) {
      const float v = s[k];
      alo = fmaf(LOF[k], v, alo);
      ahi = fmaf(HIF[k], v, ahi);
    }
    outs[c * sout + p]        = alo;
    outs[c * sout + cout + p] = ahi;
  }
}

// One synthesis level: rec[2t] = sum_m LO[2m+1]*ca[t+m] + HI[2m+1]*cd[t+m];
// rec[2t+1] uses even taps. 8 mergeable reads serve both outputs.
__device__ __forceinline__ void synth(const float* __restrict__ ins, int sin_,
                                      int cin, int pcbase,
                                      float* __restrict__ outs, int sout,
                                      int pobase, float sa, float sd, int ntr,
                                      int c, int i) {
  for (int tr = i; tr < ntr; tr += 32) {
    const float* __restrict__ pa = ins + c * sin_ + pcbase + tr;
    const float* __restrict__ pd = pa + cin;
    float eca = 0.f, ecd = 0.f, oca = 0.f, ocd = 0.f;
#pragma unroll
    for (int m = 0; m < 4; ++m) {
      const float a = pa[m], d = pd[m];
      eca = fmaf(LO[2 * m + 1], a, eca);
      ecd = fmaf(HI[2 * m + 1], d, ecd);
      oca = fmaf(LO[2 * m],     a, oca);
      ocd = fmaf(HI[2 * m],     d, ocd);
    }
    float* __restrict__ o = outs + c * sout + pobase + 2 * tr;
    o[0] = sa * eca + sd * ecd;
    o[1] = sa * oca + sd * ocd;
  }
}

} // namespace

__global__ __launch_bounds__(NT, 8) void wavemix_kernel(
    const float* __restrict__ x, const float* __restrict__ wap,
    const float* __restrict__ wdet, float* __restrict__ out) {
  __shared__ float sx[G * SX];
  __shared__ float s1[G * S1];   // [a1|d1]; a1 later overwritten by r1
  __shared__ float s2[G * S2];   // [a2|d2]; a2 later overwritten by r2
  __shared__ float s3[G * S3];   // [a3|d3]

  // Bijective XCD swizzle; consecutive wg = consecutive n-tiles of one
  // (b,dg) -> halo re-reads and shared 64B lines stay in one XCD's L2.
  const int cpx = gridDim.x >> 3;
  const int wg  = (blockIdx.x & 7) * cpx + (blockIdx.x >> 3);
  const int nt   = wg & (NTI - 1);
  const int rest = wg >> 5;               // / NTI
  const int dg   = rest % NDG;
  const int b    = rest / NDG;
  const int n0   = nt * T;
  const int d0   = dg * G;
  const int tid  = threadIdx.x;

  const size_t base = (size_t)b * N0 * DCH + d0;

  // ---- load extended x tile: float4 of 4 consecutive channels per lane.
  {
    const int q  = tid & 1;               // channel quad
    const int pl = tid >> 1;              // position slot (128)
    for (int p = pl; p < CX; p += 128) {
      const int g = refl(n0 + XLO + p, N0);
      const float4 v =
          *reinterpret_cast<const float4*>(x + base + (size_t)g * DCH + 4 * q);
      float* dst = sx + (4 * q) * SX + p;
      dst[0 * SX] = v.x; dst[1 * SX] = v.y; dst[2 * SX] = v.z; dst[3 * SX] = v.w;
    }
  }

  // compute-phase roles: wave holds channels {2w, 2w+1} -> bank parity mix
  const int c2 = tid >> 5;                // 0..7
  const int i2 = tid & 31;                // 0..31
  const float wa2 = wap[d0 + c2];
  const float wl2 = wdet[2 * DCH + d0 + c2];
  const float wl1 = wdet[1 * DCH + d0 + c2];
  __syncthreads();

  // ---- analysis
  analyze(sx, SX, n0 + XLO,        s1, S1, C1, n0 / 2 + A1LO, L1v, c2, i2);
  __syncthreads();
  analyze(s1, S1, n0 / 2 + A1LO,   s2, S2, C2, n0 / 4 + A2LO, L2v, c2, i2);
  __syncthreads();
  analyze(s2, S2, n0 / 4 + A2LO,   s3, S3, C3, n0 / 8,        L3v, c2, i2);
  __syncthreads();

  // ---- synthesis (weights folded): r2 at a2-part base 6, r1 at a1 base 18.
  // synthL3 must cover r2 coords [0 .. T/4+4] -> ntr = T/8+3 pairs.
  synth(s3, S3, C3, 0, s2, S2, 6,  wa2, wl2, T / 8 + 3, c2, i2);
  __syncthreads();
  synth(s2, S2, C2, 6, s1, S1, 18, 1.f, wl1, T / 4 + 2, c2, i2);
  __syncthreads();

  // ---- final synthesis + residual + coalesced store (channel-fast roles)
  {
    const int c = tid & 7;
    const int j = tid >> 3;               // 0..31
    const float wl0 = wdet[0 * DCH + d0 + c];
    for (int tr = j; tr < T / 2; tr += 32) {
      const float* __restrict__ pa = s1 + c * S1 + 18 + tr;
      const float* __restrict__ pd = pa + C1;
      float eca = 0.f, ecd = 0.f, oca = 0.f, ocd = 0.f;
#pragma unroll
      for (int m = 0; m < 4; ++m) {
        const float a = pa[m], d = pd[m];
        eca = fmaf(LO[2 * m + 1], a, eca);
        ecd = fmaf(HI[2 * m + 1], d, ecd);
        oca = fmaf(LO[2 * m],     a, oca);
        ocd = fmaf(HI[2 * m],     d, ocd);
      }
      const int n = 2 * tr;
      const float* __restrict__ px = sx + c * SX + (n - XLO);
      out[base + (size_t)(n0 + n) * DCH + c]     = px[0] + (eca + wl0 * ecd);
      out[base + (size_t)(n0 + n + 1) * DCH + c] = px[1] + (oca + wl0 * ocd);
    }
  }
}

extern "C" void kernel_launch(void* const* d_in, const int* in_sizes, int n_in,
                              void* d_out, int out_size, void* d_ws, size_t ws_size,
                              hipStream_t stream) {
  const float* x  = (const float*)d_in[0];
  const float* wa = (const float*)d_in[1];
  const float* wd = (const float*)d_in[2];
  float* out      = (float*)d_out;

  const int B    = in_sizes[0] / (N0 * DCH);   // 8
  const int grid = B * NDG * NTI;              // 24576, multiple of 8
  wavemix_kernel<<<grid, NT, 0, stream>>>(x, wa, wd, out);
}

// Round 5
// 61.452 us; speedup vs baseline: 1.3693x; 1.3693x over previous
//
#include <hip/hip_runtime.h>

// WaveletMixing: out = x + IDWT3(scale(DWT3(x))) along N per (b,d) channel.
// x: (B=8, N=4096, D=768) f32.
// Block = 8 channels x 256 output samples (+halo), full pipeline in one LDS
// pool (31.1 KB -> 5 blocks/CU). Interior tiles (14/16) take a refl-free
// vectorized path: analysis = 3x ds_read_b128 + 2x ds_write_b64 per 2 coeffs;
// synth/final = b128-only. Lanes stride consecutive 16B blocks -> full
// 32-bank spread. Edge tiles (nt=0,15) take a generic scalar path.

namespace {

constexpr int NT  = 256;
constexpr int N0  = 4096;
constexpr int DCH = 768;
constexpr int G   = 8;              // channels per block
constexpr int T   = 256;            // output samples per block
constexpr int NTI = N0 / T;         // 16
constexpr int NDG = DCH / G;        // 96
constexpr int L1v = 2051, L2v = 1029, L3v = 518;  // pywt symmetric lengths

// LDS pool: per-channel segments (float offsets). Stride 972 == 12 mod 32:
// channel-fast scalar phases land at exactly 2 lanes/bank (free).
constexpr int SP   = 972;
constexpr int OX   = 0;    // x tile, origin n0-46, real idx 0..351 (356 alloc)
constexpr int OA1  = 356;  // a1 origin n0/2-20 (172 real); later r1 origin n0/2
constexpr int OD1  = 536;  // d1 origin n0/2-20  (180 alloc each)
constexpr int OA2  = 716;  // a2 origin n0/4-6 (82 real); later r2 origin n0/4
constexpr int OD2  = 804;  // d2 origin n0/4-6    (88 alloc each)
constexpr int OA3  = 892;  // a3 origin n0/8 (38 real; 40 alloc)
constexpr int OD3  = 932;  // d3 origin n0/8 (40 alloc)
constexpr int OREC = 716;  // final out stage: 256 floats over dead a2|d2|a3|d3

// db4 analysis filters ascending (pywt); HI[k] = (-1)^(k+1)*LO[7-k].
__device__ constexpr float LO[8] = {
  -0.010597401784997278f,  0.032883011666982945f,  0.030841381835986965f,
  -0.18703481171888114f,  -0.02798376941698385f,   0.6308807679295904f,
   0.7148465705525415f,    0.23037781330885523f };
__device__ constexpr float HI[8] = {
  -0.23037781330885523f,   0.7148465705525415f,   -0.6308807679295904f,
  -0.02798376941698385f,   0.18703481171888114f,   0.030841381835986965f,
  -0.032883011666982945f, -0.010597401784997278f };
// Address-ascending copies: F[7-k].
__device__ constexpr float LOF[8] = {
   0.23037781330885523f,   0.7148465705525415f,    0.6308807679295904f,
  -0.02798376941698385f,  -0.18703481171888114f,   0.030841381835986965f,
   0.032883011666982945f, -0.010597401784997278f };
__device__ constexpr float HIF[8] = {
  -0.010597401784997278f, -0.032883011666982945f,  0.030841381835986965f,
   0.18703481171888114f,  -0.02798376941698385f,  -0.6308807679295904f,
   0.7148465705525415f,   -0.23037781330885523f };

__device__ __forceinline__ int refl(int g, int n) {
  g = (g < 0) ? (-g - 1) : g;
  return (g >= n) ? (2 * n - 1 - g) : g;
}

// ---------- interior (refl-free) vectorized phases ----------

// 2 outputs per task: out[2v+j] = sum_k F[k]*in[2(2v+j)+K+k], j=0,1.
template <int K>
__device__ __forceinline__ void analyze_v(const float* __restrict__ in,
                                          float* __restrict__ oa,
                                          float* __restrict__ od,
                                          int ntask, int i2) {
  for (int v = i2; v < ntask; v += 32) {
    float r[12];
#pragma unroll
    for (int j = 0; j < 3; ++j) {
      const float4 t = *reinterpret_cast<const float4*>(in + 4 * v + 4 * j);
      r[4 * j + 0] = t.x; r[4 * j + 1] = t.y;
      r[4 * j + 2] = t.z; r[4 * j + 3] = t.w;
    }
    float a0 = 0.f, h0 = 0.f, a1 = 0.f, h1 = 0.f;
#pragma unroll
    for (int k = 0; k < 8; ++k) {
      a0 = fmaf(LOF[k], r[K + k], a0);
      h0 = fmaf(HIF[k], r[K + k], h0);
      a1 = fmaf(LOF[k], r[K + 2 + k], a1);
      h1 = fmaf(HIF[k], r[K + 2 + k], h1);
    }
    *reinterpret_cast<float2*>(oa + 2 * v) = make_float2(a0, a1);
    *reinterpret_cast<float2*>(od + 2 * v) = make_float2(h0, h1);
  }
}

// 4 pairs per task: rec[2t]/rec[2t+1] for t = 4u..4u+3, same-origin ca/cd.
__device__ __forceinline__ void synth3_v(const float* __restrict__ pa,
                                         const float* __restrict__ pd,
                                         float* __restrict__ o, float sa,
                                         float sd, int ntask, int i2) {
  if (i2 < ntask) {
    const int u = i2;
    float ra[8], rd[8];
#pragma unroll
    for (int j = 0; j < 2; ++j) {
      const float4 t0 = *reinterpret_cast<const float4*>(pa + 4 * u + 4 * j);
      const float4 t1 = *reinterpret_cast<const float4*>(pd + 4 * u + 4 * j);
      ra[4*j+0] = t0.x; ra[4*j+1] = t0.y; ra[4*j+2] = t0.z; ra[4*j+3] = t0.w;
      rd[4*j+0] = t1.x; rd[4*j+1] = t1.y; rd[4*j+2] = t1.z; rd[4*j+3] = t1.w;
    }
    float ov[8];
#pragma unroll
    for (int tt = 0; tt < 4; ++tt) {
      float e = 0.f, ed = 0.f, oe = 0.f, od_ = 0.f;
#pragma unroll
      for (int m = 0; m < 4; ++m) {
        e   = fmaf(LO[2 * m + 1], ra[tt + m], e);
        ed  = fmaf(HI[2 * m + 1], rd[tt + m], ed);
        oe  = fmaf(LO[2 * m],     ra[tt + m], oe);
        od_ = fmaf(HI[2 * m],     rd[tt + m], od_);
      }
      ov[2 * tt]     = sa * e  + sd * ed;
      ov[2 * tt + 1] = sa * oe + sd * od_;
    }
    *reinterpret_cast<float4*>(o + 8 * u)     = make_float4(ov[0], ov[1], ov[2], ov[3]);
    *reinterpret_cast<float4*>(o + 8 * u + 4) = make_float4(ov[4], ov[5], ov[6], ov[7]);
  }
}

// synth level 2: ca (r2) at origin n0/4 (idx t), cd (d2) at origin n0/4-6
// (idx t+6). 4 pairs per task.
__device__ __forceinline__ void synth2_v(const float* __restrict__ pa,
                                         const float* __restrict__ pd,
                                         float* __restrict__ o, float sd,
                                         int ntask, int i2) {
  if (i2 < ntask) {
    const int u = i2;
    float ra[8], rd[12];
#pragma unroll
    for (int j = 0; j < 2; ++j) {
      const float4 t0 = *reinterpret_cast<const float4*>(pa + 4 * u + 4 * j);
      ra[4*j+0] = t0.x; ra[4*j+1] = t0.y; ra[4*j+2] = t0.z; ra[4*j+3] = t0.w;
    }
#pragma unroll
    for (int j = 0; j < 3; ++j) {
      const float4 t1 = *reinterpret_cast<const float4*>(pd + 4 * u + 4 + 4 * j);
      rd[4*j+0] = t1.x; rd[4*j+1] = t1.y; rd[4*j+2] = t1.z; rd[4*j+3] = t1.w;
    }
    float ov[8];
#pragma unroll
    for (int tt = 0; tt < 4; ++tt) {
      float e = 0.f, ed = 0.f, oe = 0.f, od_ = 0.f;
#pragma unroll
      for (int m = 0; m < 4; ++m) {
        e   = fmaf(LO[2 * m + 1], ra[tt + m], e);
        ed  = fmaf(HI[2 * m + 1], rd[tt + 2 + m], ed);  // d2 idx t+6+m
        oe  = fmaf(LO[2 * m],     ra[tt + m], oe);
        od_ = fmaf(HI[2 * m],     rd[tt + 2 + m], od_);
      }
      ov[2 * tt]     = e  + sd * ed;
      ov[2 * tt + 1] = oe + sd * od_;
    }
    *reinterpret_cast<float4*>(o + 8 * u)     = make_float4(ov[0], ov[1], ov[2], ov[3]);
    *reinterpret_cast<float4*>(o + 8 * u + 4) = make_float4(ov[4], ov[5], ov[6], ov[7]);
  }
}

// final level: r1 (origin n0/2, idx t), d1 (origin n0/2-20, idx t+20),
// residual from sx (out pos 2t -> sx idx 2t+46). 4 pairs per task (u=i2).
__device__ __forceinline__ void final_v(const float* __restrict__ pa,
                                        const float* __restrict__ pd,
                                        const float* __restrict__ px,
                                        float* __restrict__ rec, float sd,
                                        int i2) {
  const int u = i2;
  float ra[8], rd[8], rx[12];
#pragma unroll
  for (int j = 0; j < 2; ++j) {
    const float4 t0 = *reinterpret_cast<const float4*>(pa + 4 * u + 4 * j);
    const float4 t1 = *reinterpret_cast<const float4*>(pd + 4 * u + 20 + 4 * j);
    ra[4*j+0] = t0.x; ra[4*j+1] = t0.y; ra[4*j+2] = t0.z; ra[4*j+3] = t0.w;
    rd[4*j+0] = t1.x; rd[4*j+1] = t1.y; rd[4*j+2] = t1.z; rd[4*j+3] = t1.w;
  }
#pragma unroll
  for (int j = 0; j < 3; ++j) {
    const float4 t2 = *reinterpret_cast<const float4*>(px + 8 * u + 44 + 4 * j);
    rx[4*j+0] = t2.x; rx[4*j+1] = t2.y; rx[4*j+2] = t2.z; rx[4*j+3] = t2.w;
  }
  float ov[8];
#pragma unroll
  for (int tt = 0; tt < 4; ++tt) {
    float e = 0.f, ed = 0.f, oe = 0.f, od_ = 0.f;
#pragma unroll
    for (int m = 0; m < 4; ++m) {
      e   = fmaf(LO[2 * m + 1], ra[tt + m], e);
      ed  = fmaf(HI[2 * m + 1], rd[tt + m], ed);
      oe  = fmaf(LO[2 * m],     ra[tt + m], oe);
      od_ = fmaf(HI[2 * m],     rd[tt + m], od_);
    }
    ov[2 * tt]     = e  + sd * ed  + rx[2 + 2 * tt];
    ov[2 * tt + 1] = oe + sd * od_ + rx[3 + 2 * tt];
  }
  *reinterpret_cast<float4*>(rec + 8 * u)     = make_float4(ov[0], ov[1], ov[2], ov[3]);
  *reinterpret_cast<float4*>(rec + 8 * u + 4) = make_float4(ov[4], ov[5], ov[6], ov[7]);
}

// ---------- edge (generic, reflecting) scalar phases ----------

__device__ void analyze_g(const float* __restrict__ in, int Oin,
                          float* __restrict__ oa, float* __restrict__ od,
                          int cnt, int Oout, int lenout, int i2) {
  for (int p = i2; p < cnt; p += 32) {
    const int gp = refl(Oout + p, lenout);
    const int qb = 2 * gp - 6 - Oin;
    float alo = 0.f, ahi = 0.f;
#pragma unroll
    for (int k = 0; k < 8; ++k) {
      const float v = in[qb + k];
      alo = fmaf(LOF[k], v, alo);
      ahi = fmaf(HIF[k], v, ahi);
    }
    oa[p] = alo;
    od[p] = ahi;
  }
}

__device__ void synth_g(const float* __restrict__ ca,
                        const float* __restrict__ cd, int doff,
                        float* __restrict__ o, float sa, float sd, int npair,
                        int i2) {
  for (int t = i2; t < npair; t += 32) {
    float e = 0.f, ed = 0.f, oe = 0.f, od_ = 0.f;
#pragma unroll
    for (int m = 0; m < 4; ++m) {
      e   = fmaf(LO[2 * m + 1], ca[t + m], e);
      ed  = fmaf(HI[2 * m + 1], cd[t + doff + m], ed);
      oe  = fmaf(LO[2 * m],     ca[t + m], oe);
      od_ = fmaf(HI[2 * m],     cd[t + doff + m], od_);
    }
    o[2 * t]     = sa * e  + sd * ed;
    o[2 * t + 1] = sa * oe + sd * od_;
  }
}

} // namespace

__global__ __launch_bounds__(NT) void wavemix_kernel(
    const float* __restrict__ x, const float* __restrict__ wap,
    const float* __restrict__ wdet, float* __restrict__ out) {
  __shared__ float pool[G * SP];   // 31104 B

  // Bijective XCD swizzle; consecutive wg = consecutive n-tiles of one
  // (b,dg) -> halo re-reads share an XCD's L2.
  const int cpx = gridDim.x >> 3;
  const int wg  = (blockIdx.x & 7) * cpx + (blockIdx.x >> 3);
  const int nt   = wg & (NTI - 1);
  const int rest = wg >> 4;              // / NTI
  const int dg   = rest % NDG;
  const int b    = rest / NDG;
  const int n0   = nt * T;
  const int d0   = dg * G;
  const int tid  = threadIdx.x;
  const bool edge = (nt == 0) || (nt == NTI - 1);

  // ---- load x tile [n0-46 .. n0+305] (coalesced float4 over 4 channels)
  {
    const int q  = tid & 1;
    const int pl = tid >> 1;
    for (int p = pl; p < 352; p += 128) {
      int g = n0 - 46 + p;
      if (edge) g = refl(g, N0);
      const float4 v = *reinterpret_cast<const float4*>(
          x + ((size_t)b * N0 + g) * DCH + d0 + 4 * q);
      float* dst = pool + (4 * q) * SP + OX + p;
      dst[0]      = v.x;
      dst[SP]     = v.y;
      dst[2 * SP] = v.z;
      dst[3 * SP] = v.w;
    }
  }

  const int c2 = tid >> 5;   // channel (compute phases)
  const int i2 = tid & 31;   // work slot
  float* P = pool + c2 * SP;
  const float wa = wap[d0 + c2];
  const float w2 = wdet[2 * DCH + d0 + c2];
  const float w1 = wdet[1 * DCH + d0 + c2];
  const float w0 = wdet[0 * DCH + d0 + c2];
  __syncthreads();

  if (!edge) {
    // K = 2*Oout - 6 - Oin (+ relative origins): L1:0, L2:2, L3:0.
    analyze_v<0>(P + OX,  P + OA1, P + OD1, 86, i2);   // a1/d1 idx 0..171
    __syncthreads();
    analyze_v<2>(P + OA1, P + OA2, P + OD2, 44, i2);   // a2/d2 idx 0..87
    __syncthreads();
    analyze_v<0>(P + OA2, P + OA3, P + OD3, 20, i2);   // a3/d3 idx 0..39
    __syncthreads();
    synth3_v(P + OA3, P + OD3, P + OA2, wa, w2, 9, i2);  // r2 idx 0..71
    __syncthreads();
    synth2_v(P + OA2, P + OD2, P + OA1, w1, 17, i2);     // r1 idx 0..135
    __syncthreads();
    final_v(P + OA1, P + OD1, P + OX, P + OREC, w0, i2); // rec 0..255
  } else {
    analyze_g(P + OX,  n0 - 46,      P + OA1, P + OD1, 172, n0 / 2 - 20, L1v, i2);
    __syncthreads();
    analyze_g(P + OA1, n0 / 2 - 20,  P + OA2, P + OD2,  82, n0 / 4 - 6,  L2v, i2);
    __syncthreads();
    analyze_g(P + OA2, n0 / 4 - 6,   P + OA3, P + OD3,  38, n0 / 8,      L3v, i2);
    __syncthreads();
    synth_g(P + OA3, P + OD3, 0, P + OA2, wa,  w2, 35, i2);  // r2 0..69
    __syncthreads();
    synth_g(P + OA2, P + OD2, 6, P + OA1, 1.f, w1, 66, i2);  // r1 0..131
    __syncthreads();
    for (int t = i2; t < 128; t += 32) {                     // final + residual
      const float* pa = P + OA1;
      const float* pd = P + OD1;
      float e = 0.f, ed = 0.f, oe = 0.f, od_ = 0.f;
#pragma unroll
      for (int m = 0; m < 4; ++m) {
        e   = fmaf(LO[2 * m + 1], pa[t + m], e);
        ed  = fmaf(HI[2 * m + 1], pd[t + 20 + m], ed);
        oe  = fmaf(LO[2 * m],     pa[t + m], oe);
        od_ = fmaf(HI[2 * m],     pd[t + 20 + m], od_);
      }
      (P + OREC)[2 * t]     = e  + w0 * ed  + (P + OX)[2 * t + 46];
      (P + OREC)[2 * t + 1] = oe + w0 * od_ + (P + OX)[2 * t + 47];
    }
  }
  __syncthreads();

  // ---- coalesced store
  {
    const int c = tid & 7;
    const int j = tid >> 3;
    const float* R = pool + c * SP + OREC;
    float* orow = out + ((size_t)b * N0 + n0) * DCH + d0 + c;
    for (int pos = j; pos < T; pos += 32)
      orow[(size_t)pos * DCH] = R[pos];
  }
}

extern "C" void kernel_launch(void* const* d_in, const int* in_sizes, int n_in,
                              void* d_out, int out_size, void* d_ws, size_t ws_size,
                              hipStream_t stream) {
  const float* x  = (const float*)d_in[0];
  const float* wa = (const float*)d_in[1];
  const float* wd = (const float*)d_in[2];
  float* out      = (float*)d_out;

  const int B    = in_sizes[0] / (N0 * DCH);   // 8
  const int grid = B * NDG * NTI;              // 12288, multiple of 8
  wavemix_kernel<<<grid, NT, 0, stream>>>(x, wa, wd, out);
}